// Round 1
// baseline (703.118 us; speedup 1.0000x reference)
//
#include <hip/hip_runtime.h>
#include <hip/hip_bf16.h>

// Problem: B=32, Q=16, F=4096, E=256, NL=8, L=2 residual layers per mapper.
#define B_   32
#define Q_   16
#define F_   4096
#define E_   256
#define NL_  8
#define LAY_ 2
#define FT   64     // feature rows per chunk
#define CH   4      // chunks per block
#define NT   16     // tile-blocks per batch  (FT*CH*NT == F_)
#define TPB  256    // 4 waves

typedef __attribute__((ext_vector_type(8))) __bf16 bf16x8_t;
typedef __attribute__((ext_vector_type(4))) float  f32x4;

// ---- LDS swizzle for the [64][256] bf16 tile (row stride 512 B) ----
// XOR bits 4-6 of the in-row byte offset with a function of the row so that
// (a) b128 A-fragment reads (16 rows, same k) hit distinct 16B slots (2-way max)
// (b) scalar column reads (8 rows stride 1, fixed e) spread over 4 bank octets.
__device__ __forceinline__ int swz(int r) {
  return ((r & 7) << 4) ^ (((r >> 3) & 3) << 5);
}
__device__ __forceinline__ int xoff(int r, int c2) {  // c2 = byte offset in row [0,512)
  return r * 512 + (c2 ^ swz(r));
}

__device__ __forceinline__ unsigned short f2bf_bits(float f) {
  __bf16 h = (__bf16)f;
  return __builtin_bit_cast(unsigned short, h);
}

// ---------------- kernel 0: weight prep (fp32 [l][k][n] -> bf16 [l][n][k]) ----
__global__ __launch_bounds__(256) void prep_kernel(
    const float* __restrict__ Wf, const float* __restrict__ Wv,
    unsigned short* __restrict__ WtF, unsigned short* __restrict__ WtV) {
  int idx = blockIdx.x * 256 + threadIdx.x;   // 4*65536 total
  int ml = idx >> 16;                         // 0,1: Wf layers; 2,3: Wv layers
  int r  = idx & 0xFFFF;
  int n  = r >> 8, k = r & 255;
  const float* src = (ml < 2) ? (Wf + ml * 65536) : (Wv + (ml - 2) * 65536);
  unsigned short* dst = (ml < 2) ? (WtF + ml * 65536) : (WtV + (ml - 2) * 65536);
  dst[n * 256 + k] = f2bf_bits(src[k * 256 + n]);
}

// ---------------- kernel 1: q mapper (fp32), store bf16 qm ------------------
__global__ __launch_bounds__(256) void qmap_kernel(
    const float* __restrict__ query, const float* __restrict__ Wq,
    const float* __restrict__ bq, unsigned short* __restrict__ qmb) {
  int b = blockIdx.x, t = threadIdx.x;
  __shared__ float xq[Q_][E_ + 1];
  for (int j = 0; j < Q_; ++j) xq[j][t] = query[(b * Q_ + j) * E_ + t];
  __syncthreads();
  for (int l = 0; l < LAY_; ++l) {
    const float* W = Wq + l * E_ * E_;
    float acc[Q_];
#pragma unroll
    for (int r = 0; r < Q_; ++r) acc[r] = 0.f;
    for (int k = 0; k < E_; ++k) {
      float wv = W[k * E_ + t];
#pragma unroll
      for (int r = 0; r < Q_; ++r) acc[r] += xq[r][k] * wv;
    }
    float be = bq[l * E_ + t];
    __syncthreads();
#pragma unroll
    for (int r = 0; r < Q_; ++r) xq[r][t] = fmaxf(acc[r] + be, 0.f) + xq[r][t];
    __syncthreads();
  }
  for (int j = 0; j < Q_; ++j) qmb[(b * Q_ + j) * E_ + t] = f2bf_bits(xq[j][t]);
}

// ---------------- fused main kernel -----------------------------------------
__device__ __forceinline__ void stage_tile(char* Xs, const float* __restrict__ src, int tid) {
#pragma unroll
  for (int j = 0; j < 8; ++j) {
    int u  = j * 256 + tid;        // 16B-unit index, 2048 units
    int r  = u >> 5;               // row
    int cb = (u & 31) << 4;        // byte in row
    const float4* s4 = (const float4*)(src + r * E_ + ((u & 31) << 3));
    float4 v0 = s4[0], v1 = s4[1];
    bf16x8_t t;
    t[0] = (__bf16)v0.x; t[1] = (__bf16)v0.y; t[2] = (__bf16)v0.z; t[3] = (__bf16)v0.w;
    t[4] = (__bf16)v1.x; t[5] = (__bf16)v1.y; t[6] = (__bf16)v1.z; t[7] = (__bf16)v1.w;
    *(bf16x8_t*)(Xs + xoff(r, cb)) = t;
  }
}

// One residual layer, in-place on the LDS tile. Wave w owns cols [w*64, w*64+64).
__device__ __forceinline__ void mapper_layer(char* Xs, const unsigned short* __restrict__ Wt,
                                             const float* __restrict__ bias, int w, int lane) {
  f32x4 acc[4][4];
#pragma unroll
  for (int mf = 0; mf < 4; ++mf)
#pragma unroll
    for (int nf = 0; nf < 4; ++nf) acc[mf][nf] = (f32x4){0.f, 0.f, 0.f, 0.f};
  const int m0 = lane & 15;
  const int kb = (lane >> 4) << 3;
  for (int ks = 0; ks < 8; ++ks) {
    const int k = ks * 32 + kb;
    bf16x8_t a[4];
#pragma unroll
    for (int mf = 0; mf < 4; ++mf)
      a[mf] = *(const bf16x8_t*)(Xs + xoff(mf * 16 + m0, k << 1));
#pragma unroll
    for (int nf = 0; nf < 4; ++nf) {
      const int n = w * 64 + nf * 16 + m0;
      bf16x8_t bb = *(const bf16x8_t*)(Wt + n * E_ + k);
#pragma unroll
      for (int mf = 0; mf < 4; ++mf)
        acc[mf][nf] = __builtin_amdgcn_mfma_f32_16x16x32_bf16(a[mf], bb, acc[mf][nf], 0, 0, 0);
    }
  }
  __syncthreads();   // all K-loop reads of Xs done before in-place update
#pragma unroll
  for (int nf = 0; nf < 4; ++nf) {
    const int e = w * 64 + nf * 16 + m0;
    const float be = bias[e];
#pragma unroll
    for (int mf = 0; mf < 4; ++mf) {
#pragma unroll
      for (int r = 0; r < 4; ++r) {
        const int row = mf * 16 + ((lane >> 4) << 2) + r;
        __bf16* p = (__bf16*)(Xs + xoff(row, e << 1));
        float xv = (float)(*p);                       // residual (pre-layer x)
        float v  = fmaxf(acc[mf][nf][r] + be, 0.f) + xv;
        *p = (__bf16)v;
      }
    }
  }
  __syncthreads();
}

__global__ __launch_bounds__(TPB, 2) void fused_kernel(
    const float* __restrict__ features, const float* __restrict__ values,
    const float* __restrict__ amask, const float* __restrict__ ftw,
    const unsigned short* __restrict__ WtF, const float* __restrict__ bfb,
    const unsigned short* __restrict__ WtV, const float* __restrict__ bvb,
    const unsigned short* __restrict__ qmb, float* __restrict__ partials) {
  const int bid = blockIdx.x;
  const int b = bid / NT, tb = bid % NT;
  const int tid = threadIdx.x;
  const int lane = tid & 63, w = tid >> 6;

  __shared__ __align__(128) char Xs[FT * 512];            // 32 KB bf16 tile (swizzled)
  __shared__ __align__(16) unsigned short Ws[Q_][FT + 8]; // attn weights [q][f] bf16

  f32x4 pacc[4];
#pragma unroll
  for (int nf = 0; nf < 4; ++nf) pacc[nf] = (f32x4){0.f, 0.f, 0.f, 0.f};

  const int m0 = lane & 15;
  const int kb = (lane >> 4) << 3;

  for (int c = 0; c < CH; ++c) {
    const int f0 = (tb * CH + c) * FT;

    // ---- features tile -> Xs, f-mapper (2 layers) ----
    stage_tile(Xs, features + (size_t)(b * F_ + f0) * E_, tid);
    __syncthreads();
    mapper_layer(Xs, WtF, bfb, w, lane);
    mapper_layer(Xs, WtF + 65536, bfb + E_, w, lane);

    // ---- S = Fm @ qm^T (wave w owns f rows [w*16, w*16+16)) ----
    {
      f32x4 s = (f32x4){0.f, 0.f, 0.f, 0.f};
      const int arow = w * 16 + m0;
      const unsigned short* qrow = qmb + (size_t)(b * Q_ + m0) * E_ + kb;
      for (int ks = 0; ks < 8; ++ks) {
        bf16x8_t a = *(const bf16x8_t*)(Xs + xoff(arow, (ks * 32 + kb) << 1));
        bf16x8_t bb = *(const bf16x8_t*)(qrow + ks * 32);
        s = __builtin_amdgcn_mfma_f32_16x16x32_bf16(a, bb, s, 0, 0, 0);
      }
      const int q = m0;  // D: col = q
#pragma unroll
      for (int r = 0; r < 4; ++r) {
        const int fl = w * 16 + ((lane >> 4) << 2) + r;
        const int fg = f0 + fl;
        float lw = ftw[b * F_ + fg] * amask[b * F_ + fg];
        float sg = 1.f / (1.f + __expf(-s[r]));
        Ws[q][fl] = f2bf_bits(sg * lw);
      }
    }
    __syncthreads();

    // ---- values tile -> Xs, v-mapper (2 layers) ----
    stage_tile(Xs, values + (size_t)(b * F_ + f0) * E_, tid);
    __syncthreads();
    mapper_layer(Xs, WtV, bvb, w, lane);
    mapper_layer(Xs, WtV + 65536, bvb + E_, w, lane);

    // ---- P += w[16,FT] @ Vm[FT,256]  (wave w owns cols [w*64, w*64+64)) ----
    {
#pragma unroll
      for (int ks = 0; ks < FT / 32; ++ks) {
        bf16x8_t a = *(const bf16x8_t*)&Ws[m0][ks * 32 + kb];
#pragma unroll
        for (int nf = 0; nf < 4; ++nf) {
          const int e = w * 64 + nf * 16 + m0;
          bf16x8_t bb;
#pragma unroll
          for (int i = 0; i < 8; ++i) {
            const int f = ks * 32 + kb + i;
            bb[i] = *(const __bf16*)(Xs + xoff(f, e << 1));
          }
          pacc[nf] = __builtin_amdgcn_mfma_f32_16x16x32_bf16(a, bb, pacc[nf], 0, 0, 0);
        }
      }
    }
    __syncthreads();  // protect Xs/Ws before next chunk overwrites
  }

  // ---- write pooled partials [b][tb][q][e] ----
#pragma unroll
  for (int nf = 0; nf < 4; ++nf) {
    const int e = w * 64 + nf * 16 + m0;
#pragma unroll
    for (int r = 0; r < 4; ++r) {
      const int q = ((lane >> 4) << 2) + r;
      partials[(((size_t)b * NT + tb) * Q_ + q) * E_ + e] = pacc[nf][r];
    }
  }
}

// ---------------- kernel 3: reduce partials + c-mapper + output -------------
__global__ __launch_bounds__(256) void tail_kernel(
    const float* __restrict__ partials, const float* __restrict__ Wc,
    const float* __restrict__ bc, const float* __restrict__ Wout,
    const float* __restrict__ bout, float* __restrict__ out) {
  int b = blockIdx.x, t = threadIdx.x;
  __shared__ float xp[Q_][E_ + 1];
  for (int q = 0; q < Q_; ++q) {
    float s = 0.f;
    for (int tb = 0; tb < NT; ++tb)
      s += partials[(((size_t)b * NT + tb) * Q_ + q) * E_ + t];
    xp[q][t] = s;
  }
  __syncthreads();
  for (int l = 0; l < LAY_; ++l) {
    const float* W = Wc + l * E_ * E_;
    float acc[Q_];
#pragma unroll
    for (int r = 0; r < Q_; ++r) acc[r] = 0.f;
    for (int k = 0; k < E_; ++k) {
      float wv = W[k * E_ + t];
#pragma unroll
      for (int r = 0; r < Q_; ++r) acc[r] += xp[r][k] * wv;
    }
    float be = bc[l * E_ + t];
    __syncthreads();
#pragma unroll
    for (int r = 0; r < Q_; ++r) xp[r][t] = fmaxf(acc[r] + be, 0.f) + xp[r][t];
    __syncthreads();
  }
  if (t < Q_ * NL_) {
    int q = t / NL_, n = t % NL_;
    float s = bout[n];
    for (int k = 0; k < E_; ++k) s += xp[q][k] * Wout[k * NL_ + n];
    out[(b * Q_ + q) * NL_ + n] = s;
  }
}

// ---------------- launch -----------------------------------------------------
extern "C" void kernel_launch(void* const* d_in, const int* in_sizes, int n_in,
                              void* d_out, int out_size, void* d_ws, size_t ws_size,
                              hipStream_t stream) {
  (void)in_sizes; (void)n_in; (void)out_size; (void)ws_size;
  const float* query    = (const float*)d_in[0];
  const float* features = (const float*)d_in[1];
  const float* values   = (const float*)d_in[2];
  const float* amask    = (const float*)d_in[3];
  const float* ftw      = (const float*)d_in[4];
  const float* Wq       = (const float*)d_in[5];
  const float* bq       = (const float*)d_in[6];
  const float* Wf       = (const float*)d_in[7];
  const float* bfb      = (const float*)d_in[8];
  const float* Wv       = (const float*)d_in[9];
  const float* bvb      = (const float*)d_in[10];
  const float* Wc       = (const float*)d_in[11];
  const float* bcb      = (const float*)d_in[12];
  const float* Wout     = (const float*)d_in[13];
  const float* bout     = (const float*)d_in[14];
  float* out = (float*)d_out;

  char* ws = (char*)d_ws;
  unsigned short* WtF = (unsigned short*)(ws);            // 256 KB
  unsigned short* WtV = (unsigned short*)(ws + 262144);   // 256 KB
  unsigned short* qmb = (unsigned short*)(ws + 524288);   // 256 KB
  float* partials     = (float*)(ws + 786432);            // 8 MB

  prep_kernel<<<1024, 256, 0, stream>>>(Wf, Wv, WtF, WtV);
  qmap_kernel<<<B_, 256, 0, stream>>>(query, Wq, bq, qmb);
  fused_kernel<<<B_ * NT, TPB, 0, stream>>>(features, values, amask, ftw,
                                            WtF, bfb, WtV, bvb, qmb, partials);
  tail_kernel<<<B_, 256, 0, stream>>>(partials, Wc, bcb, Wout, bout, out);
}